// Round 9
// baseline (269.731 us; speedup 1.0000x reference)
//
#include <hip/hip_runtime.h>
#include <math.h>

#define EDIM 1024
#define NH   16
#define HD   64
#define BATCH 2
#define SEQ  2048
#define NROW (BATCH*SEQ)   // 4096
#define YAT_EPS 0.1f

typedef _Float16 f16;
typedef _Float16 f16x8 __attribute__((ext_vector_type(8)));
typedef _Float16 f16x4 __attribute__((ext_vector_type(4)));
typedef __fp16   h16x2 __attribute__((ext_vector_type(2)));   // cvt_pkrtz native type
typedef float    f32x4 __attribute__((ext_vector_type(4)));

static __device__ __forceinline__ int pk2(float a, float b) {
    union { h16x2 h; int i; } u;
    u.h = __builtin_amdgcn_cvt_pkrtz(a, b);
    return u.i;
}
static __device__ __forceinline__ f16x8 cvt_f16x8(float4 a, float4 b) {
    union { int i[4]; f16x8 h; } u;
    u.i[0] = pk2(a.x, a.y);
    u.i[1] = pk2(a.z, a.w);
    u.i[2] = pk2(b.x, b.y);
    u.i[3] = pk2(b.z, b.w);
    return u.h;
}

// ---------------------------------------------------------------------------
// 4x fused: W [1024 k][1024 n] fp32 -> Wt [1024 n][1024 k] f16 (32x32 tiles)
// ---------------------------------------------------------------------------
__global__ __launch_bounds__(256)
void transcast4_kernel(const float* __restrict__ W0, const float* __restrict__ W1,
                       const float* __restrict__ W2, const float* __restrict__ W3,
                       f16* __restrict__ T0, f16* __restrict__ T1,
                       f16* __restrict__ T2, f16* __restrict__ T3)
{
    const int z = blockIdx.z;
    const float* W = (z == 0) ? W0 : (z == 1) ? W1 : (z == 2) ? W2 : W3;
    f16*         Wt = (z == 0) ? T0 : (z == 1) ? T1 : (z == 2) ? T2 : T3;

    __shared__ float T[32][33];
    const int t = threadIdx.x;
    const int r = t >> 3, c4 = (t & 7) * 4;
    const int bi = blockIdx.x * 32, bj = blockIdx.y * 32;
    const float4 v = *(const float4*)(W + (size_t)(bi + r) * 1024 + bj + c4);
    T[r][c4 + 0] = v.x; T[r][c4 + 1] = v.y; T[r][c4 + 2] = v.z; T[r][c4 + 3] = v.w;
    __syncthreads();
    f16x4 o = {(f16)T[c4 + 0][r], (f16)T[c4 + 1][r], (f16)T[c4 + 2][r], (f16)T[c4 + 3][r]};
    *(f16x4*)(Wt + (size_t)(bj + r) * 1024 + bi + c4) = o;
}

// ---------------------------------------------------------------------------
// MFMA GEMM (unchanged from round 8): register-staged pipeline; fp32->f16
// cast of A fused into staging when AF32. BM x 128, BK=32, LDS dbuf.
// epi: 0 = fp32 [M,N]; 1 = l2norm -> f16 [b,h,s,d]; 2 = f16 [b,h,d,s].
// ---------------------------------------------------------------------------
template<int BM, bool AF32>
__global__ __launch_bounds__(256)
void gemm_f16(const void* __restrict__ Av,
              const f16* __restrict__ B0, const f16* __restrict__ B1, const f16* __restrict__ B2,
              const float* __restrict__ bi0, const float* __restrict__ bi1, const float* __restrict__ bi2,
              void* __restrict__ o0, void* __restrict__ o1, void* __restrict__ o2,
              int e0, int e1, int e2)
{
    constexpr int MT   = BM / 32;
    constexpr int LA   = BM / 64;
    constexpr int ABUF = BM * 32;
    constexpr int BBUF = 128 * 32;
    constexpr int STG  = 2 * (ABUF + BBUF) * 2;
    constexpr int EPI  = BM * 128 * 2;
    constexpr int LDSB = STG > EPI ? STG : EPI;
    __shared__ __align__(16) char lds[LDSB];
    f16* As = (f16*)lds;
    f16* Bs = (f16*)lds + 2 * ABUF;

    const int z = blockIdx.z;
    const f16*   Bt   = (z == 0) ? B0  : (z == 1) ? B1  : B2;
    const float* bias = (z == 0) ? bi0 : (z == 1) ? bi1 : bi2;
    void*        Cout = (z == 0) ? o0  : (z == 1) ? o1  : o2;
    const int    epi  = (z == 0) ? e0  : (z == 1) ? e1  : e2;

    const int tid  = threadIdx.x;
    const int lane = tid & 63;
    const int w    = tid >> 6;
    const int cl   = lane & 15;
    const int quad = lane >> 4;
    const int wm = w & 1, wn = w >> 1;
    const int bm = blockIdx.x * BM, bn = blockIdx.y * 128;
    const int wmoff = wm * (MT * 16);

    const int srow = tid >> 2;
    const int sc   = tid & 3;
    const int ssw  = (sc ^ (srow & 3)) * 8;
    const float* gAf = (const float*)Av + (size_t)(bm + srow) * 1024 + sc * 8;
    const f16*   gAh = (const f16*)Av   + (size_t)(bm + srow) * 1024 + sc * 8;
    const f16*   gB  = Bt + (size_t)(bn + srow) * 1024 + sc * 8;
    int lAo[LA], lBo[2];
#pragma unroll
    for (int i = 0; i < LA; ++i) lAo[i] = (srow + i * 64) * 32 + ssw;
#pragma unroll
    for (int i = 0; i < 2;  ++i) lBo[i] = (srow + i * 64) * 32 + ssw;

    f32x4 acc[MT][4];
#pragma unroll
    for (int i = 0; i < MT; ++i)
#pragma unroll
        for (int j = 0; j < 4; ++j) acc[i][j] = (f32x4){0.f, 0.f, 0.f, 0.f};

    f16x8 ra[LA], rb[2];

#define LOAD_A(i, kn) (AF32 ? cvt_f16x8(*(const float4*)(gAf + (size_t)(i) * 64 * 1024 + (kn)),      \
                                        *(const float4*)(gAf + (size_t)(i) * 64 * 1024 + (kn) + 4))  \
                            : *(const f16x8*)(gAh + (size_t)(i) * 64 * 1024 + (kn)))

#pragma unroll
    for (int i = 0; i < LA; ++i) ra[i] = LOAD_A(i, 0);
#pragma unroll
    for (int i = 0; i < 2;  ++i) rb[i] = *(const f16x8*)(gB + (size_t)i * 64 * 1024);
#pragma unroll
    for (int i = 0; i < LA; ++i) *(f16x8*)(As + lAo[i]) = ra[i];
#pragma unroll
    for (int i = 0; i < 2;  ++i) *(f16x8*)(Bs + lBo[i]) = rb[i];
#pragma unroll
    for (int i = 0; i < LA; ++i) ra[i] = LOAD_A(i, 32);
#pragma unroll
    for (int i = 0; i < 2;  ++i) rb[i] = *(const f16x8*)(gB + (size_t)i * 64 * 1024 + 32);
    __syncthreads();

    const int fsw = (quad ^ (cl & 3)) * 8;

    for (int it = 0; it < 32; ++it) {
        const int buf = it & 1, nb = buf ^ 1;
        if (it < 31) {
#pragma unroll
            for (int i = 0; i < LA; ++i) *(f16x8*)(As + nb * ABUF + lAo[i]) = ra[i];
#pragma unroll
            for (int i = 0; i < 2;  ++i) *(f16x8*)(Bs + nb * BBUF + lBo[i]) = rb[i];
        }
        if (it < 30) {
            const int kn = (it + 2) * 32;
#pragma unroll
            for (int i = 0; i < LA; ++i) ra[i] = LOAD_A(i, kn);
#pragma unroll
            for (int i = 0; i < 2;  ++i) rb[i] = *(const f16x8*)(gB + (size_t)i * 64 * 1024 + kn);
        }
        f16x8 af[MT], bf[4];
#pragma unroll
        for (int mt = 0; mt < MT; ++mt)
            af[mt] = *(const f16x8*)(&As[buf * ABUF + (wmoff + mt * 16 + cl) * 32 + fsw]);
#pragma unroll
        for (int nt = 0; nt < 4; ++nt)
            bf[nt] = *(const f16x8*)(&Bs[buf * BBUF + (wn * 64 + nt * 16 + cl) * 32 + fsw]);
#pragma unroll
        for (int mt = 0; mt < MT; ++mt)
#pragma unroll
            for (int nt = 0; nt < 4; ++nt)
                acc[mt][nt] = __builtin_amdgcn_mfma_f32_16x16x32_f16(af[mt], bf[nt], acc[mt][nt], 0, 0, 0);
        __syncthreads();
    }
#undef LOAD_A

    float bcol[4];
#pragma unroll
    for (int nt = 0; nt < 4; ++nt) bcol[nt] = bias[bn + wn * 64 + nt * 16 + cl];
#pragma unroll
    for (int mt = 0; mt < MT; ++mt)
#pragma unroll
        for (int nt = 0; nt < 4; ++nt)
#pragma unroll
            for (int rg = 0; rg < 4; ++rg) acc[mt][nt][rg] += bcol[nt];

    const int b_idx = bm >> 11, sl0 = bm & (SEQ - 1), h0 = bn >> 6;

    if (epi == 0) {
        float* C = (float*)Cout;
#pragma unroll
        for (int mt = 0; mt < MT; ++mt)
#pragma unroll
            for (int rg = 0; rg < 4; ++rg) {
                const int row = bm + wmoff + mt * 16 + quad * 4 + rg;
#pragma unroll
                for (int nt = 0; nt < 4; ++nt)
                    C[(size_t)row * EDIM + bn + wn * 64 + nt * 16 + cl] = acc[mt][nt][rg];
            }
    } else if (epi == 1) {                // l2norm -> f16 [b,h,s,d]
        f16* C = (f16*)Cout;
        __syncthreads();
        f16* S = (f16*)lds;
#pragma unroll
        for (int mt = 0; mt < MT; ++mt)
#pragma unroll
            for (int rg = 0; rg < 4; ++rg) {
                float ss = 0.f;
#pragma unroll
                for (int nt = 0; nt < 4; ++nt) ss += acc[mt][nt][rg] * acc[mt][nt][rg];
                ss += __shfl_xor(ss, 1); ss += __shfl_xor(ss, 2);
                ss += __shfl_xor(ss, 4); ss += __shfl_xor(ss, 8);
                const float inv = 1.0f / (sqrtf(ss) + 1e-8f);
                const int row = wmoff + mt * 16 + quad * 4 + rg;
#pragma unroll
                for (int nt = 0; nt < 4; ++nt) {
                    const int col = wn * 64 + nt * 16 + cl;
                    S[row * 128 + (((col >> 3) ^ (row & 15)) * 8) + (col & 7)] =
                        (f16)(acc[mt][nt][rg] * inv);
                }
            }
        __syncthreads();
#pragma unroll
        for (int i = 0; i < BM / 16; ++i) {
            const int c = tid + i * 256;
            const int s = c >> 4, gi = c & 15;
            f16x8 v = *(const f16x8*)(&S[s * 128 + ((gi ^ (s & 15)) * 8)]);
            const int head = h0 + (gi >> 3), d8 = (gi & 7) * 8;
            *(f16x8*)(C + ((size_t)(b_idx * NH + head) * SEQ + sl0 + s) * HD + d8) = v;
        }
    } else {                              // epi==2: f16 transposed [b,h,d,s]
        f16* C = (f16*)Cout;
        __syncthreads();
        f16* S = (f16*)lds;
        constexpr int GM = BM / 8 - 1;
#pragma unroll
        for (int mt = 0; mt < MT; ++mt) {
            const int s0 = wmoff + mt * 16 + quad * 4;
#pragma unroll
            for (int nt = 0; nt < 4; ++nt) {
                const int col = wn * 64 + nt * 16 + cl;
                f16x4 o = {(f16)acc[mt][nt][0], (f16)acc[mt][nt][1],
                           (f16)acc[mt][nt][2], (f16)acc[mt][nt][3]};
                *(f16x4*)(&S[col * BM + (((s0 >> 3) ^ (col & GM)) * 8) + (s0 & 7)]) = o;
            }
        }
        __syncthreads();
        constexpr int GSH = (BM == 128) ? 4 : 3;
#pragma unroll
        for (int i = 0; i < BM / 16; ++i) {
            const int c = tid + i * 256;
            const int col = c >> GSH, gi = c & GM;
            f16x8 v = *(const f16x8*)(&S[col * BM + ((gi ^ (col & GM)) * 8)]);
            const int head = h0 + (col >> 6), d = col & 63;
            *(f16x8*)(C + ((size_t)(b_idx * NH + head) * HD + d) * SEQ + sl0 + gi * 8) = v;
        }
    }
}

// ---------------------------------------------------------------------------
// Yat attention, round 9: NO LDS for Q/K/V — MFMA fragments loaded directly
// from global (L1/L2-hot tiles), zero barriers in the k-loop (waves stream
// independently). 512 threads = 8 waves (4 wm x 2 wk), 32q/wave, 64-k tiles.
// K frags prefetched 1 tile ahead; V frags issued a phase early.
// P via wave-private LDS roundtrip (stride-36 pad, conflict-free).
// LDS 33.8 KB: P regions 8 x 2304 B; epilogue reuses as rs_s/Ox.
// ---------------------------------------------------------------------------
__global__ __launch_bounds__(512, 4)
void yat_attn(const f16* __restrict__ Qh, const f16* __restrict__ Kh,
              const f16* __restrict__ Vt, f16* __restrict__ AO)
{
    __shared__ __align__(16) char lds[33792];

    const int tid  = threadIdx.x;
    const int lane = tid & 63;
    const int w    = tid >> 6;
    const int cl   = lane & 15;
    const int quad = lane >> 4;
    const int wm = w & 3;                   // q quarter (32 q)
    const int wk = w >> 2;                  // k half (32 k)
    const int q0 = blockIdx.x * 128;
    const int bh = blockIdx.y;

    const f16* Qg = Qh + (size_t)bh * SEQ * HD;
    const f16* Kg = Kh + (size_t)bh * SEQ * HD;
    const f16* Vg = Vt + (size_t)bh * HD * SEQ;

    // Q B-fragments, loaded once directly from global
    f16x8 qf[2][2];
#pragma unroll
    for (int qt = 0; qt < 2; ++qt)
#pragma unroll
        for (int kb = 0; kb < 2; ++kb)
            qf[qt][kb] = *(const f16x8*)(Qg + (size_t)(q0 + wm * 32 + qt * 16 + cl) * HD +
                                         (kb * 4 + quad) * 8);

    // fragment base pointers (this lane's slice)
    const f16* gKf = Kg + (size_t)(wk * 32 + cl) * HD + quad * 8;   // + t*64*HD + kt*16*HD + kb*32
    const f16* gVf = Vg + (size_t)cl * SEQ + wk * 32 + quad * 8;    // + dn*16*SEQ + t*64

    f16* Pw = (f16*)lds + w * 1152;         // wave-private P: 32 q x 36 f16

    f32x4 O[2][4];
    float rs[2] = {0.f, 0.f};
#pragma unroll
    for (int i = 0; i < 2; ++i)
#pragma unroll
        for (int j = 0; j < 4; ++j) O[i][j] = (f32x4){0.f, 0.f, 0.f, 0.f};

    // K frags for tile 0
    f16x8 kc[4];
#pragma unroll
    for (int kt = 0; kt < 2; ++kt)
#pragma unroll
        for (int kb = 0; kb < 2; ++kb)
            kc[kt * 2 + kb] = *(const f16x8*)(gKf + (size_t)(kt * 16) * HD + kb * 32);

#pragma unroll 2
    for (int t = 0; t < 32; ++t) {
        // V frags for tile t (consumed after S+scores: ample slack)
        f16x8 vc[4];
#pragma unroll
        for (int dn = 0; dn < 4; ++dn)
            vc[dn] = *(const f16x8*)(gVf + (size_t)(dn * 16) * SEQ + t * 64);
        // K frags for tile t+1 (consumed next iteration)
        f16x8 kn[4];
        if (t < 31) {
#pragma unroll
            for (int kt = 0; kt < 2; ++kt)
#pragma unroll
                for (int kb = 0; kb < 2; ++kb)
                    kn[kt * 2 + kb] = *(const f16x8*)(gKf + (size_t)((t + 1) * 64 + kt * 16) * HD + kb * 32);
        }

        // ---- S^T (32k x 32q) = K.Q^T ----
        f32x4 s[2][2];
#pragma unroll
        for (int kt = 0; kt < 2; ++kt)
#pragma unroll
            for (int qt = 0; qt < 2; ++qt) s[kt][qt] = (f32x4){0.f, 0.f, 0.f, 0.f};
#pragma unroll
        for (int kb = 0; kb < 2; ++kb)
#pragma unroll
            for (int qt = 0; qt < 2; ++qt) {
                s[0][qt] = __builtin_amdgcn_mfma_f32_16x16x32_f16(kc[0 * 2 + kb], qf[qt][kb], s[0][qt], 0, 0, 0);
                s[1][qt] = __builtin_amdgcn_mfma_f32_16x16x32_f16(kc[1 * 2 + kb], qf[qt][kb], s[1][qt], 0, 0, 0);
            }

        // ---- yat scores p = 4.41*rcp(u) + u - 4.2, u = 1.1 - d; P -> LDS ----
#pragma unroll
        for (int kt = 0; kt < 2; ++kt)
#pragma unroll
            for (int qt = 0; qt < 2; ++qt) {
                float p[4];
#pragma unroll
                for (int rg = 0; rg < 4; ++rg) {
                    const float u = (1.0f + YAT_EPS) - s[kt][qt][rg];
                    p[rg] = fmaf(4.41f, __builtin_amdgcn_rcpf(u), u - 4.2f);
                    rs[qt] += p[rg];
                }
                union { int i[2]; f16x4 h; } pk;
                pk.i[0] = pk2(p[0], p[1]);
                pk.i[1] = pk2(p[2], p[3]);
                *(f16x4*)(&Pw[(qt * 16 + cl) * 36 + kt * 16 + quad * 4]) = pk.h;
            }

        // ---- P A-frags (same-wave LDS, in-order; no barrier) ----
        f16x8 pa[2];
#pragma unroll
        for (int qt = 0; qt < 2; ++qt)
            pa[qt] = *(const f16x8*)(&Pw[(qt * 16 + cl) * 36 + quad * 8]);

        // ---- O += P.V (K=32) ----
#pragma unroll
        for (int dn = 0; dn < 4; ++dn)
#pragma unroll
            for (int qt = 0; qt < 2; ++qt)
                O[qt][dn] = __builtin_amdgcn_mfma_f32_16x16x32_f16(pa[qt], vc[dn], O[qt][dn], 0, 0, 0);

#pragma unroll
        for (int i = 0; i < 4; ++i) kc[i] = kn[i];
    }

    // ---- epilogue: cross-wk reduce rs and O, normalize, store ----
    __syncthreads();
    float* rs_s = (float*)lds;              // 256 f32
    float* Ox   = (float*)(lds + 1024);     // 128 x 64 f32 (32 KB)

#pragma unroll
    for (int qt = 0; qt < 2; ++qt) {
        float t = rs[qt];
        t += __shfl_xor(t, 16);
        t += __shfl_xor(t, 32);
        if (quad == 0) rs_s[wk * 128 + wm * 32 + qt * 16 + cl] = t;
    }
    if (wk == 1) {
#pragma unroll
        for (int qt = 0; qt < 2; ++qt)
#pragma unroll
            for (int dn = 0; dn < 4; ++dn)
#pragma unroll
                for (int rg = 0; rg < 4; ++rg)
                    Ox[(wm * 32 + qt * 16 + quad * 4 + rg) * 64 + dn * 16 + cl] = O[qt][dn][rg];
    }
    __syncthreads();
    if (wk == 0) {
        const int b = bh >> 4, h = bh & 15;
#pragma unroll
        for (int qt = 0; qt < 2; ++qt)
#pragma unroll
            for (int rg = 0; rg < 4; ++rg) {
                const int ql = wm * 32 + qt * 16 + quad * 4 + rg;
                const float tot = rs_s[ql] + rs_s[128 + ql];
                const float inv = 1.0f / (tot + 1e-6f);
                const size_t rowoff = ((size_t)b * SEQ + q0 + ql) * EDIM + h * 64;
#pragma unroll
                for (int dn = 0; dn < 4; ++dn)
                    AO[rowoff + dn * 16 + cl] =
                        (f16)((O[qt][dn][rg] + Ox[ql * 64 + dn * 16 + cl]) * inv);
            }
    }
}

// ---------------------------------------------------------------------------
extern "C" void kernel_launch(void* const* d_in, const int* in_sizes, int n_in,
                              void* d_out, int out_size, void* d_ws, size_t ws_size,
                              hipStream_t stream)
{
    const float* x  = (const float*)d_in[0];
    const float* Wq = (const float*)d_in[1];
    const float* bq = (const float*)d_in[2];
    const float* Wk = (const float*)d_in[3];
    const float* bk = (const float*)d_in[4];
    const float* Wv = (const float*)d_in[5];
    const float* bv = (const float*)d_in[6];
    const float* Wo = (const float*)d_in[7];
    const float* bo = (const float*)d_in[8];

    char* p = (char*)d_ws;
    f16* Wqt = (f16*)p;                 p += (size_t)EDIM * EDIM * 2;   // 2 MB
    f16* Wkt = (f16*)p;                 p += (size_t)EDIM * EDIM * 2;
    f16* Wvt = (f16*)p;                 p += (size_t)EDIM * EDIM * 2;
    f16* Wot = (f16*)p;                 p += (size_t)EDIM * EDIM * 2;
    f16* Qhb = (f16*)p;                 p += (size_t)NROW * EDIM * 2;   // [b,h,s,d]
    f16* Khb = (f16*)p;                 p += (size_t)NROW * EDIM * 2;
    f16* Vtb = (f16*)p;                 p += (size_t)NROW * EDIM * 2;   // [b,h,d,s]
    f16* AOb = (f16*)p;                 p += (size_t)NROW * EDIM * 2;   // [b,s,e]

    transcast4_kernel<<<dim3(32, 32, 4), 256, 0, stream>>>(Wq, Wk, Wv, Wo,
                                                           Wqt, Wkt, Wvt, Wot);

    gemm_f16<128, true><<<dim3(NROW / 128, EDIM / 128, 3), 256, 0, stream>>>(
        x, Wqt, Wkt, Wvt, bq, bk, bv, Qhb, Khb, Vtb, 1, 1, 2);

    yat_attn<<<dim3(SEQ / 128, BATCH * NH), 512, 0, stream>>>(Qhb, Khb, Vtb, AOb);

    gemm_f16<64, false><<<dim3(NROW / 64, EDIM / 128, 1), 256, 0, stream>>>(
        AOb, Wot, Wot, Wot, bo, bo, bo, d_out, d_out, d_out, 0, 0, 0);
}

// Round 10
// 204.399 us; speedup vs baseline: 1.3196x; 1.3196x over previous
//
#include <hip/hip_runtime.h>
#include <math.h>

#define EDIM 1024
#define NH   16
#define HD   64
#define BATCH 2
#define SEQ  2048
#define NROW (BATCH*SEQ)   // 4096
#define YAT_EPS 0.1f

typedef _Float16 f16;
typedef _Float16 f16x8 __attribute__((ext_vector_type(8)));
typedef _Float16 f16x4 __attribute__((ext_vector_type(4)));
typedef __fp16   h16x2 __attribute__((ext_vector_type(2)));   // cvt_pkrtz native type
typedef float    f32x4 __attribute__((ext_vector_type(4)));

static __device__ __forceinline__ int pk2(float a, float b) {
    union { h16x2 h; int i; } u;
    u.h = __builtin_amdgcn_cvt_pkrtz(a, b);
    return u.i;
}

// ---------------------------------------------------------------------------
// fp32 -> f16 elementwise cast (x). 4 elems/thread.
// ---------------------------------------------------------------------------
__global__ __launch_bounds__(256)
void cast_f16_kernel(const float* __restrict__ src, f16* __restrict__ dst)
{
    const int i = (blockIdx.x * 256 + threadIdx.x) * 4;
    const float4 v = *(const float4*)(src + i);
    union { int i[2]; f16x4 h; } o;
    o.i[0] = pk2(v.x, v.y);
    o.i[1] = pk2(v.z, v.w);
    *(f16x4*)(dst + i) = o.h;
}

// ---------------------------------------------------------------------------
// 4x fused: W [1024 k][1024 n] fp32 -> Wt [1024 n][1024 k] f16 (32x32 tiles)
// ---------------------------------------------------------------------------
__global__ __launch_bounds__(256)
void transcast4_kernel(const float* __restrict__ W0, const float* __restrict__ W1,
                       const float* __restrict__ W2, const float* __restrict__ W3,
                       f16* __restrict__ T0, f16* __restrict__ T1,
                       f16* __restrict__ T2, f16* __restrict__ T3)
{
    const int z = blockIdx.z;
    const float* W = (z == 0) ? W0 : (z == 1) ? W1 : (z == 2) ? W2 : W3;
    f16*         Wt = (z == 0) ? T0 : (z == 1) ? T1 : (z == 2) ? T2 : T3;

    __shared__ float T[32][33];
    const int t = threadIdx.x;
    const int r = t >> 3, c4 = (t & 7) * 4;
    const int bi = blockIdx.x * 32, bj = blockIdx.y * 32;
    const float4 v = *(const float4*)(W + (size_t)(bi + r) * 1024 + bj + c4);
    T[r][c4 + 0] = v.x; T[r][c4 + 1] = v.y; T[r][c4 + 2] = v.z; T[r][c4 + 3] = v.w;
    __syncthreads();
    f16x4 o = {(f16)T[c4 + 0][r], (f16)T[c4 + 1][r], (f16)T[c4 + 2][r], (f16)T[c4 + 3][r]};
    *(f16x4*)(Wt + (size_t)(bj + r) * 1024 + bi + c4) = o;
}

// ---------------------------------------------------------------------------
// MFMA GEMM, round 10: 128 x BN tile (BN=256 for QKV: halves B-panel traffic;
// BN=128 for O-proj). Register-staged dbuf pipeline (r8 structure, unchanged).
// NT = 2*BN threads; per-wave work identical in both configs (64x64, 4x4 frags).
// epi: 0 = fp32 [M,N]; 1 = l2norm -> f16 [b,h,s,d]; 2 = f16 [b,h,d,s].
// epi1/2 (BN=256 only) stage output in two 32KB LDS halves, coalesced stores.
// ---------------------------------------------------------------------------
template<int BN>
__global__ __launch_bounds__(BN * 2, 2)
void gemm_f16(const f16* __restrict__ A,
              const f16* __restrict__ B0, const f16* __restrict__ B1, const f16* __restrict__ B2,
              const float* __restrict__ bi0, const float* __restrict__ bi1, const float* __restrict__ bi2,
              void* __restrict__ o0, void* __restrict__ o1, void* __restrict__ o2,
              int e0, int e1, int e2)
{
    constexpr int NT   = BN * 2;            // threads
    constexpr int SR   = NT / 4;            // staging rows per slot-pass
    constexpr int ASL  = 128 / SR;          // A slots per thread
    constexpr int BSL  = BN / SR;           // B slots per thread (=2)
    constexpr int ABUF = 128 * 32;          // f16 per A slab
    constexpr int BBUF = BN * 32;           // f16 per B slab
    __shared__ __align__(16) char lds[2 * (ABUF + BBUF) * 2];
    f16* As = (f16*)lds;
    f16* Bs = (f16*)lds + 2 * ABUF;

    const int z = blockIdx.z;
    const f16*   Bt   = (z == 0) ? B0  : (z == 1) ? B1  : B2;
    const float* bias = (z == 0) ? bi0 : (z == 1) ? bi1 : bi2;
    void*        Cout = (z == 0) ? o0  : (z == 1) ? o1  : o2;
    const int    epi  = (z == 0) ? e0  : (z == 1) ? e1  : e2;

    const int tid  = threadIdx.x;
    const int lane = tid & 63;
    const int w    = tid >> 6;
    const int cl   = lane & 15;
    const int quad = lane >> 4;
    const int wm = w & 1, wn = w >> 1;      // wn: 0..1 (BN=128) or 0..3 (BN=256)
    const int bm = blockIdx.x * 128, bn = blockIdx.y * BN;
    const int wmoff = wm * 64;

    const int srow = tid >> 2;              // 0..SR-1
    const int sc   = tid & 3;
    const int ssw  = (sc ^ (srow & 3)) * 8;
    const f16* gA = A  + (size_t)(bm + srow) * 1024 + sc * 8;
    const f16* gB = Bt + (size_t)(bn + srow) * 1024 + sc * 8;
    int lAo[ASL], lBo[BSL];
#pragma unroll
    for (int i = 0; i < ASL; ++i) lAo[i] = (srow + i * SR) * 32 + ssw;
#pragma unroll
    for (int i = 0; i < BSL; ++i) lBo[i] = (srow + i * SR) * 32 + ssw;

    f32x4 acc[4][4];
#pragma unroll
    for (int i = 0; i < 4; ++i)
#pragma unroll
        for (int j = 0; j < 4; ++j) acc[i][j] = (f32x4){0.f, 0.f, 0.f, 0.f};

    f16x8 ra[ASL], rb[BSL];

    // prologue: slab 0 -> regs -> LDS buf0; slab 1 -> regs
#pragma unroll
    for (int i = 0; i < ASL; ++i) ra[i] = *(const f16x8*)(gA + (size_t)i * SR * 1024);
#pragma unroll
    for (int i = 0; i < BSL; ++i) rb[i] = *(const f16x8*)(gB + (size_t)i * SR * 1024);
#pragma unroll
    for (int i = 0; i < ASL; ++i) *(f16x8*)(As + lAo[i]) = ra[i];
#pragma unroll
    for (int i = 0; i < BSL; ++i) *(f16x8*)(Bs + lBo[i]) = rb[i];
#pragma unroll
    for (int i = 0; i < ASL; ++i) ra[i] = *(const f16x8*)(gA + (size_t)i * SR * 1024 + 32);
#pragma unroll
    for (int i = 0; i < BSL; ++i) rb[i] = *(const f16x8*)(gB + (size_t)i * SR * 1024 + 32);
    __syncthreads();

    const int fsw = (quad ^ (cl & 3)) * 8;

    for (int it = 0; it < 32; ++it) {
        const int buf = it & 1, nb = buf ^ 1;
        if (it < 31) {                    // publish slab it+1 (regs -> LDS)
#pragma unroll
            for (int i = 0; i < ASL; ++i) *(f16x8*)(As + nb * ABUF + lAo[i]) = ra[i];
#pragma unroll
            for (int i = 0; i < BSL; ++i) *(f16x8*)(Bs + nb * BBUF + lBo[i]) = rb[i];
        }
        if (it < 30) {                    // issue loads for slab it+2 (in flight across barrier)
            const int kn = (it + 2) * 32;
#pragma unroll
            for (int i = 0; i < ASL; ++i) ra[i] = *(const f16x8*)(gA + (size_t)i * SR * 1024 + kn);
#pragma unroll
            for (int i = 0; i < BSL; ++i) rb[i] = *(const f16x8*)(gB + (size_t)i * SR * 1024 + kn);
        }
        f16x8 af[4], bf[4];
#pragma unroll
        for (int mt = 0; mt < 4; ++mt)
            af[mt] = *(const f16x8*)(&As[buf * ABUF + (wmoff + mt * 16 + cl) * 32 + fsw]);
#pragma unroll
        for (int nt = 0; nt < 4; ++nt)
            bf[nt] = *(const f16x8*)(&Bs[buf * BBUF + (wn * 64 + nt * 16 + cl) * 32 + fsw]);
#pragma unroll
        for (int mt = 0; mt < 4; ++mt)
#pragma unroll
            for (int nt = 0; nt < 4; ++nt)
                acc[mt][nt] = __builtin_amdgcn_mfma_f32_16x16x32_f16(af[mt], bf[nt], acc[mt][nt], 0, 0, 0);
        __syncthreads();                  // lgkm drain only
    }

    float bcol[4];
#pragma unroll
    for (int nt = 0; nt < 4; ++nt) bcol[nt] = bias[bn + wn * 64 + nt * 16 + cl];
#pragma unroll
    for (int mt = 0; mt < 4; ++mt)
#pragma unroll
        for (int nt = 0; nt < 4; ++nt)
#pragma unroll
            for (int rg = 0; rg < 4; ++rg) acc[mt][nt][rg] += bcol[nt];

    const int b_idx = bm >> 11, sl0 = bm & (SEQ - 1), h0 = bn >> 6;

    if (epi == 0) {                       // fp32 plain [M,N] (O-projection)
        float* C = (float*)Cout;
#pragma unroll
        for (int mt = 0; mt < 4; ++mt)
#pragma unroll
            for (int rg = 0; rg < 4; ++rg) {
                const int row = bm + wmoff + mt * 16 + quad * 4 + rg;
#pragma unroll
                for (int nt = 0; nt < 4; ++nt)
                    C[(size_t)row * EDIM + bn + wn * 64 + nt * 16 + cl] = acc[mt][nt][rg];
            }
    } else if (epi == 1) {                // l2norm -> f16 [b,h,s,d], two 128-col halves
        f16* C = (f16*)Cout;
        f16* S = (f16*)lds;               // [128 s][128 col] per half, granule swizzle
#pragma unroll
        for (int h = 0; h < 2; ++h) {
            __syncthreads();
            if ((wn >> 1) == h) {
#pragma unroll
                for (int mt = 0; mt < 4; ++mt)
#pragma unroll
                    for (int rg = 0; rg < 4; ++rg) {
                        float ss = 0.f;
#pragma unroll
                        for (int nt = 0; nt < 4; ++nt) ss += acc[mt][nt][rg] * acc[mt][nt][rg];
                        ss += __shfl_xor(ss, 1); ss += __shfl_xor(ss, 2);
                        ss += __shfl_xor(ss, 4); ss += __shfl_xor(ss, 8);
                        const float inv = 1.0f / (sqrtf(ss) + 1e-8f);
                        const int row = wmoff + mt * 16 + quad * 4 + rg;
#pragma unroll
                        for (int nt = 0; nt < 4; ++nt) {
                            const int colh = (wn & 1) * 64 + nt * 16 + cl;
                            S[row * 128 + (((colh >> 3) ^ (row & 15)) * 8) + (colh & 7)] =
                                (f16)(acc[mt][nt][rg] * inv);
                        }
                    }
            }
            __syncthreads();
#pragma unroll
            for (int i = 0; i < 4; ++i) {
                const int c = tid + i * NT;         // 2048 chunks of 16B
                const int s = c >> 4, gi = c & 15;
                f16x8 v = *(const f16x8*)(&S[s * 128 + ((gi ^ (s & 15)) * 8)]);
                const int head = h0 + h * 2 + (gi >> 3), d8 = (gi & 7) * 8;
                *(f16x8*)(C + ((size_t)(b_idx * NH + head) * SEQ + sl0 + s) * HD + d8) = v;
            }
        }
    } else {                              // epi==2: f16 transposed [b,h,d,s], two halves
        f16* C = (f16*)Cout;
        f16* S = (f16*)lds;               // [128 col][128 s] per half
#pragma unroll
        for (int h = 0; h < 2; ++h) {
            __syncthreads();
            if ((wn >> 1) == h) {
#pragma unroll
                for (int mt = 0; mt < 4; ++mt) {
                    const int s0 = wmoff + mt * 16 + quad * 4;
#pragma unroll
                    for (int nt = 0; nt < 4; ++nt) {
                        const int colh = (wn & 1) * 64 + nt * 16 + cl;
                        f16x4 o = {(f16)acc[mt][nt][0], (f16)acc[mt][nt][1],
                                   (f16)acc[mt][nt][2], (f16)acc[mt][nt][3]};
                        *(f16x4*)(&S[colh * 128 + (((s0 >> 3) ^ (colh & 15)) * 8) + (s0 & 7)]) = o;
                    }
                }
            }
            __syncthreads();
#pragma unroll
            for (int i = 0; i < 4; ++i) {
                const int c = tid + i * NT;         // 2048 chunks of 16B
                const int colh = c >> 4, gi = c & 15;
                f16x8 v = *(const f16x8*)(&S[colh * 128 + ((gi ^ (colh & 15)) * 8)]);
                const int head = h0 + h * 2 + (colh >> 6), d = colh & 63;
                *(f16x8*)(C + ((size_t)(b_idx * NH + head) * HD + d) * SEQ + sl0 + gi * 8) = v;
            }
        }
    }
}

// ---------------------------------------------------------------------------
// Yat attention — EXACT round-8 kernel (64.7 µs known): 512 threads
// (8 waves = 4 wm x 2 wk), 128-q tile, 64-k tiles register-staged + dbuf
// (1 barrier/iter, lgkm-only drain). S^T = K.Q^T; P C->A layout in-register
// via ds_bpermute; PV K=32. LDS 48 KB.
// ---------------------------------------------------------------------------
__global__ __launch_bounds__(512, 4)
void yat_attn(const f16* __restrict__ Qh, const f16* __restrict__ Kh,
              const f16* __restrict__ Vt, f16* __restrict__ AO)
{
    __shared__ __align__(16) char lds[49152];
    f16* Qs = (f16*)lds;                    // 128 x 64
    f16* KB = (f16*)(lds + 16384);          // 2 bufs x 4096 f16
    f16* VB = (f16*)(lds + 32768);          // 2 bufs x 4096 f16

    const int tid  = threadIdx.x;
    const int lane = tid & 63;
    const int w    = tid >> 6;
    const int cl   = lane & 15;
    const int quad = lane >> 4;
    const int wm = w & 3;                   // q quarter (32 q)
    const int wk = w >> 2;                  // k half (32 k)
    const int q0 = blockIdx.x * 128;
    const int bh = blockIdx.y;

    const f16* Qg = Qh + (size_t)bh * SEQ * HD;
    const f16* Kg = Kh + (size_t)bh * SEQ * HD;
    const f16* Vg = Vt + (size_t)bh * HD * SEQ;

    const int rkv = tid >> 3;               // 0..63
    const int gkv = tid & 7;
    const f16* gK = Kg + (size_t)rkv * HD + gkv * 8;
    const f16* gV = Vg + (size_t)rkv * SEQ + gkv * 8;
    const int lkOff = rkv * 64 + ((gkv ^ (rkv & 7)) * 8);

    f16x8 kr = *(const f16x8*)(gK);
    f16x8 vr = *(const f16x8*)(gV);

#pragma unroll
    for (int i = 0; i < 2; ++i) {
        const int s0 = tid + i * 512;
        const int row = s0 >> 3, g = s0 & 7;
        f16x8 v = *(const f16x8*)(Qg + (size_t)(q0 + row) * HD + g * 8);
        *(f16x8*)(&Qs[row * 64 + ((g ^ (row & 7)) * 8)]) = v;
    }
    __syncthreads();
    f16x8 qf[2][2];
#pragma unroll
    for (int qt = 0; qt < 2; ++qt)
#pragma unroll
        for (int kb = 0; kb < 2; ++kb)
            qf[qt][kb] = *(const f16x8*)(&Qs[(wm * 32 + qt * 16 + cl) * 64 +
                                             ((kb * 4 + quad) ^ (cl & 7)) * 8]);

    f32x4 O[2][4];
    float rs[2] = {0.f, 0.f};
#pragma unroll
    for (int i = 0; i < 2; ++i)
#pragma unroll
        for (int j = 0; j < 4; ++j) O[i][j] = (f32x4){0.f, 0.f, 0.f, 0.f};

    const int addrA = ((((quad & 1) << 1) * 16) + cl) << 2;
    const int addrB = addrA + 64;

    for (int t = 0; t < 32; ++t) {
        const int buf = t & 1;
        *(f16x8*)(&KB[buf * 4096 + lkOff]) = kr;
        *(f16x8*)(&VB[buf * 4096 + lkOff]) = vr;
        if (t < 31) {
            kr = *(const f16x8*)(gK + (size_t)(t + 1) * 64 * HD);
            vr = *(const f16x8*)(gV + (t + 1) * 64);
        }
        __syncthreads();

        const f16* Ks = KB + buf * 4096;
        const f16* Vs = VB + buf * 4096;

        f32x4 s[2][2];
#pragma unroll
        for (int kt = 0; kt < 2; ++kt)
#pragma unroll
            for (int qt = 0; qt < 2; ++qt) s[kt][qt] = (f32x4){0.f, 0.f, 0.f, 0.f};
#pragma unroll
        for (int kb = 0; kb < 2; ++kb) {
            const int sw = ((kb * 4 + quad) ^ (cl & 7)) * 8;
            f16x8 af0 = *(const f16x8*)(&Ks[(wk * 32 +  0 + cl) * 64 + sw]);
            f16x8 af1 = *(const f16x8*)(&Ks[(wk * 32 + 16 + cl) * 64 + sw]);
#pragma unroll
            for (int qt = 0; qt < 2; ++qt) {
                s[0][qt] = __builtin_amdgcn_mfma_f32_16x16x32_f16(af0, qf[qt][kb], s[0][qt], 0, 0, 0);
                s[1][qt] = __builtin_amdgcn_mfma_f32_16x16x32_f16(af1, qf[qt][kb], s[1][qt], 0, 0, 0);
            }
        }

        int pks[2][2][2];
#pragma unroll
        for (int kt = 0; kt < 2; ++kt)
#pragma unroll
            for (int qt = 0; qt < 2; ++qt) {
                float p[4];
#pragma unroll
                for (int rg = 0; rg < 4; ++rg) {
                    const float u = (1.0f + YAT_EPS) - s[kt][qt][rg];
                    p[rg] = fmaf(4.41f, __builtin_amdgcn_rcpf(u), u - 4.2f);
                    rs[qt] += p[rg];
                }
                pks[kt][qt][0] = pk2(p[0], p[1]);
                pks[kt][qt][1] = pk2(p[2], p[3]);
            }

        f16x8 pa[2];
#pragma unroll
        for (int qt = 0; qt < 2; ++qt) {
            union { int i[4]; f16x8 h; } u;
#pragma unroll
            for (int j = 0; j < 2; ++j) {
                int a0 = __builtin_amdgcn_ds_bpermute(addrA, pks[0][qt][j]);
                int a1 = __builtin_amdgcn_ds_bpermute(addrA, pks[1][qt][j]);
                u.i[j]     = (quad >= 2) ? a1 : a0;
                int b0 = __builtin_amdgcn_ds_bpermute(addrB, pks[0][qt][j]);
                int b1 = __builtin_amdgcn_ds_bpermute(addrB, pks[1][qt][j]);
                u.i[j + 2] = (quad >= 2) ? b1 : b0;
            }
            pa[qt] = u.h;
        }

#pragma unroll
        for (int dn = 0; dn < 4; ++dn) {
            f16x8 vb = *(const f16x8*)(&Vs[(dn * 16 + cl) * 64 +
                                           ((wk * 4 + quad) ^ (cl & 7)) * 8]);
#pragma unroll
            for (int qt = 0; qt < 2; ++qt)
                O[qt][dn] = __builtin_amdgcn_mfma_f32_16x16x32_f16(pa[qt], vb, O[qt][dn], 0, 0, 0);
        }
    }

    __syncthreads();
    float* rs_s = (float*)lds;
    float* Ox   = (float*)(lds + 1024);

#pragma unroll
    for (int qt = 0; qt < 2; ++qt) {
        float t = rs[qt];
        t += __shfl_xor(t, 16);
        t += __shfl_xor(t, 32);
        if (quad == 0) rs_s[wk * 128 + wm * 32 + qt * 16 + cl] = t;
    }
    if (wk == 1) {
#pragma unroll
        for (int qt = 0; qt < 2; ++qt)
#pragma unroll
            for (int dn = 0; dn < 4; ++dn)
#pragma unroll
                for (int rg = 0; rg < 4; ++rg)
                    Ox[(wm * 32 + qt * 16 + quad * 4 + rg) * 64 + dn * 16 + cl] = O[qt][dn][rg];
    }
    __syncthreads();
    if (wk == 0) {
        const int b = bh >> 4, h = bh & 15;
#pragma unroll
        for (int qt = 0; qt < 2; ++qt)
#pragma unroll
            for (int rg = 0; rg < 4; ++rg) {
                const int ql = wm * 32 + qt * 16 + quad * 4 + rg;
                const float tot = rs_s[ql] + rs_s[128 + ql];
                const float inv = 1.0f / (tot + 1e-6f);
                const size_t rowoff = ((size_t)b * SEQ + q0 + ql) * EDIM + h * 64;
#pragma unroll
                for (int dn = 0; dn < 4; ++dn)
                    AO[rowoff + dn * 16 + cl] =
                        (f16)((O[qt][dn][rg] + Ox[ql * 64 + dn * 16 + cl]) * inv);
            }
    }
}

// ---------------------------------------------------------------------------
extern "C" void kernel_launch(void* const* d_in, const int* in_sizes, int n_in,
                              void* d_out, int out_size, void* d_ws, size_t ws_size,
                              hipStream_t stream)
{
    const float* x  = (const float*)d_in[0];
    const float* Wq = (const float*)d_in[1];
    const float* bq = (const float*)d_in[2];
    const float* Wk = (const float*)d_in[3];
    const float* bk = (const float*)d_in[4];
    const float* Wv = (const float*)d_in[5];
    const float* bv = (const float*)d_in[6];
    const float* Wo = (const float*)d_in[7];
    const float* bo = (const float*)d_in[8];

    char* p = (char*)d_ws;
    f16* xb  = (f16*)p;                 p += (size_t)NROW * EDIM * 2;   // 8 MB
    f16* Wqt = (f16*)p;                 p += (size_t)EDIM * EDIM * 2;   // 2 MB
    f16* Wkt = (f16*)p;                 p += (size_t)EDIM * EDIM * 2;
    f16* Wvt = (f16*)p;                 p += (size_t)EDIM * EDIM * 2;
    f16* Wot = (f16*)p;                 p += (size_t)EDIM * EDIM * 2;
    f16* Qhb = (f16*)p;                 p += (size_t)NROW * EDIM * 2;   // [b,h,s,d]
    f16* Khb = (f16*)p;                 p += (size_t)NROW * EDIM * 2;
    f16* Vtb = (f16*)p;                 p += (size_t)NROW * EDIM * 2;   // [b,h,d,s]
    f16* AOb = (f16*)p;                 p += (size_t)NROW * EDIM * 2;   // [b,s,e]

    cast_f16_kernel<<<NROW * EDIM / 1024, 256, 0, stream>>>(x, xb);
    transcast4_kernel<<<dim3(32, 32, 4), 256, 0, stream>>>(Wq, Wk, Wv, Wo,
                                                           Wqt, Wkt, Wvt, Wot);

    // fused Q/K/V projections: 128x256 tiles -> 384 blocks, 512 threads
    gemm_f16<256><<<dim3(NROW / 128, EDIM / 256, 3), 512, 0, stream>>>(
        xb, Wqt, Wkt, Wvt, bq, bk, bv, Qhb, Khb, Vtb, 1, 1, 2);

    yat_attn<<<dim3(SEQ / 128, BATCH * NH), 512, 0, stream>>>(Qhb, Khb, Vtb, AOb);

    // output projection: 128x128 tiles -> 256 blocks, 256 threads
    gemm_f16<128><<<dim3(NROW / 128, EDIM / 128, 1), 256, 0, stream>>>(
        AOb, Wot, Wot, Wot, bo, bo, bo, d_out, d_out, d_out, 0, 0, 0);
}

// Round 11
// 201.577 us; speedup vs baseline: 1.3381x; 1.0140x over previous
//
#include <hip/hip_runtime.h>
#include <math.h>

#define EDIM 1024
#define NH   16
#define HD   64
#define BATCH 2
#define SEQ  2048
#define NROW (BATCH*SEQ)   // 4096
#define YAT_EPS 0.1f

typedef _Float16 f16;
typedef _Float16 f16x8 __attribute__((ext_vector_type(8)));
typedef _Float16 f16x4 __attribute__((ext_vector_type(4)));
typedef __fp16   h16x2 __attribute__((ext_vector_type(2)));   // cvt_pkrtz native type
typedef float    f32x4 __attribute__((ext_vector_type(4)));

static __device__ __forceinline__ int pk2(float a, float b) {
    union { h16x2 h; int i; } u;
    u.h = __builtin_amdgcn_cvt_pkrtz(a, b);
    return u.i;
}

// ---------------------------------------------------------------------------
// prep kernel (1 launch replaces cast + transcast4):
// z<4 : W_z [1024 k][1024 n] fp32 -> Wt_z [n][k] f16 (32x32 LDS transpose)
// z==4: x fp32 -> f16 flat cast (4096 f32 per block)
// ---------------------------------------------------------------------------
__global__ __launch_bounds__(256)
void prep_kernel(const float* __restrict__ x, f16* __restrict__ xb,
                 const float* __restrict__ W0, const float* __restrict__ W1,
                 const float* __restrict__ W2, const float* __restrict__ W3,
                 f16* __restrict__ T0, f16* __restrict__ T1,
                 f16* __restrict__ T2, f16* __restrict__ T3)
{
    const int z = blockIdx.z;
    if (z == 4) {
        const int bid = blockIdx.y * 32 + blockIdx.x;
#pragma unroll
        for (int i = 0; i < 4; ++i) {
            const int off = bid * 4096 + i * 1024 + threadIdx.x * 4;
            const float4 v = *(const float4*)(x + off);
            union { int i2[2]; f16x4 h; } o;
            o.i2[0] = pk2(v.x, v.y);
            o.i2[1] = pk2(v.z, v.w);
            *(f16x4*)(xb + off) = o.h;
        }
        return;
    }
    const float* W = (z == 0) ? W0 : (z == 1) ? W1 : (z == 2) ? W2 : W3;
    f16*         Wt = (z == 0) ? T0 : (z == 1) ? T1 : (z == 2) ? T2 : T3;

    __shared__ float T[32][33];
    const int t = threadIdx.x;
    const int r = t >> 3, c4 = (t & 7) * 4;
    const int bi = blockIdx.x * 32, bj = blockIdx.y * 32;
    const float4 v = *(const float4*)(W + (size_t)(bi + r) * 1024 + bj + c4);
    T[r][c4 + 0] = v.x; T[r][c4 + 1] = v.y; T[r][c4 + 2] = v.z; T[r][c4 + 3] = v.w;
    __syncthreads();
    f16x4 o = {(f16)T[c4 + 0][r], (f16)T[c4 + 1][r], (f16)T[c4 + 2][r], (f16)T[c4 + 3][r]};
    *(f16x4*)(Wt + (size_t)(bj + r) * 1024 + bi + c4) = o;
}

// ---------------------------------------------------------------------------
// MFMA GEMM (unchanged from round 10): 128 x BN tile, register-staged dbuf.
// epi: 0 = fp32 [M,N]; 1 = l2norm -> f16 [b,h,s,d]; 2 = f16 [b,h,d,s].
// ---------------------------------------------------------------------------
template<int BN>
__global__ __launch_bounds__(BN * 2, 2)
void gemm_f16(const f16* __restrict__ A,
              const f16* __restrict__ B0, const f16* __restrict__ B1, const f16* __restrict__ B2,
              const float* __restrict__ bi0, const float* __restrict__ bi1, const float* __restrict__ bi2,
              void* __restrict__ o0, void* __restrict__ o1, void* __restrict__ o2,
              int e0, int e1, int e2)
{
    constexpr int NT   = BN * 2;
    constexpr int SR   = NT / 4;
    constexpr int ASL  = 128 / SR;
    constexpr int BSL  = BN / SR;
    constexpr int ABUF = 128 * 32;
    constexpr int BBUF = BN * 32;
    __shared__ __align__(16) char lds[2 * (ABUF + BBUF) * 2];
    f16* As = (f16*)lds;
    f16* Bs = (f16*)lds + 2 * ABUF;

    const int z = blockIdx.z;
    const f16*   Bt   = (z == 0) ? B0  : (z == 1) ? B1  : B2;
    const float* bias = (z == 0) ? bi0 : (z == 1) ? bi1 : bi2;
    void*        Cout = (z == 0) ? o0  : (z == 1) ? o1  : o2;
    const int    epi  = (z == 0) ? e0  : (z == 1) ? e1  : e2;

    const int tid  = threadIdx.x;
    const int lane = tid & 63;
    const int w    = tid >> 6;
    const int cl   = lane & 15;
    const int quad = lane >> 4;
    const int wm = w & 1, wn = w >> 1;
    const int bm = blockIdx.x * 128, bn = blockIdx.y * BN;
    const int wmoff = wm * 64;

    const int srow = tid >> 2;
    const int sc   = tid & 3;
    const int ssw  = (sc ^ (srow & 3)) * 8;
    const f16* gA = A  + (size_t)(bm + srow) * 1024 + sc * 8;
    const f16* gB = Bt + (size_t)(bn + srow) * 1024 + sc * 8;
    int lAo[ASL], lBo[BSL];
#pragma unroll
    for (int i = 0; i < ASL; ++i) lAo[i] = (srow + i * SR) * 32 + ssw;
#pragma unroll
    for (int i = 0; i < BSL; ++i) lBo[i] = (srow + i * SR) * 32 + ssw;

    f32x4 acc[4][4];
#pragma unroll
    for (int i = 0; i < 4; ++i)
#pragma unroll
        for (int j = 0; j < 4; ++j) acc[i][j] = (f32x4){0.f, 0.f, 0.f, 0.f};

    f16x8 ra[ASL], rb[BSL];

#pragma unroll
    for (int i = 0; i < ASL; ++i) ra[i] = *(const f16x8*)(gA + (size_t)i * SR * 1024);
#pragma unroll
    for (int i = 0; i < BSL; ++i) rb[i] = *(const f16x8*)(gB + (size_t)i * SR * 1024);
#pragma unroll
    for (int i = 0; i < ASL; ++i) *(f16x8*)(As + lAo[i]) = ra[i];
#pragma unroll
    for (int i = 0; i < BSL; ++i) *(f16x8*)(Bs + lBo[i]) = rb[i];
#pragma unroll
    for (int i = 0; i < ASL; ++i) ra[i] = *(const f16x8*)(gA + (size_t)i * SR * 1024 + 32);
#pragma unroll
    for (int i = 0; i < BSL; ++i) rb[i] = *(const f16x8*)(gB + (size_t)i * SR * 1024 + 32);
    __syncthreads();

    const int fsw = (quad ^ (cl & 3)) * 8;

    for (int it = 0; it < 32; ++it) {
        const int buf = it & 1, nb = buf ^ 1;
        if (it < 31) {
#pragma unroll
            for (int i = 0; i < ASL; ++i) *(f16x8*)(As + nb * ABUF + lAo[i]) = ra[i];
#pragma unroll
            for (int i = 0; i < BSL; ++i) *(f16x8*)(Bs + nb * BBUF + lBo[i]) = rb[i];
        }
        if (it < 30) {
            const int kn = (it + 2) * 32;
#pragma unroll
            for (int i = 0; i < ASL; ++i) ra[i] = *(const f16x8*)(gA + (size_t)i * SR * 1024 + kn);
#pragma unroll
            for (int i = 0; i < BSL; ++i) rb[i] = *(const f16x8*)(gB + (size_t)i * SR * 1024 + kn);
        }
        f16x8 af[4], bf[4];
#pragma unroll
        for (int mt = 0; mt < 4; ++mt)
            af[mt] = *(const f16x8*)(&As[buf * ABUF + (wmoff + mt * 16 + cl) * 32 + fsw]);
#pragma unroll
        for (int nt = 0; nt < 4; ++nt)
            bf[nt] = *(const f16x8*)(&Bs[buf * BBUF + (wn * 64 + nt * 16 + cl) * 32 + fsw]);
#pragma unroll
        for (int mt = 0; mt < 4; ++mt)
#pragma unroll
            for (int nt = 0; nt < 4; ++nt)
                acc[mt][nt] = __builtin_amdgcn_mfma_f32_16x16x32_f16(af[mt], bf[nt], acc[mt][nt], 0, 0, 0);
        __syncthreads();
    }

    float bcol[4];
#pragma unroll
    for (int nt = 0; nt < 4; ++nt) bcol[nt] = bias[bn + wn * 64 + nt * 16 + cl];
#pragma unroll
    for (int mt = 0; mt < 4; ++mt)
#pragma unroll
        for (int nt = 0; nt < 4; ++nt)
#pragma unroll
            for (int rg = 0; rg < 4; ++rg) acc[mt][nt][rg] += bcol[nt];

    const int b_idx = bm >> 11, sl0 = bm & (SEQ - 1), h0 = bn >> 6;

    if (epi == 0) {
        float* C = (float*)Cout;
#pragma unroll
        for (int mt = 0; mt < 4; ++mt)
#pragma unroll
            for (int rg = 0; rg < 4; ++rg) {
                const int row = bm + wmoff + mt * 16 + quad * 4 + rg;
#pragma unroll
                for (int nt = 0; nt < 4; ++nt)
                    C[(size_t)row * EDIM + bn + wn * 64 + nt * 16 + cl] = acc[mt][nt][rg];
            }
    } else if (epi == 1) {                // l2norm -> f16 [b,h,s,d], two 128-col halves
        f16* C = (f16*)Cout;
        f16* S = (f16*)lds;
#pragma unroll
        for (int h = 0; h < 2; ++h) {
            __syncthreads();
            if ((wn >> 1) == h) {
#pragma unroll
                for (int mt = 0; mt < 4; ++mt)
#pragma unroll
                    for (int rg = 0; rg < 4; ++rg) {
                        float ss = 0.f;
#pragma unroll
                        for (int nt = 0; nt < 4; ++nt) ss += acc[mt][nt][rg] * acc[mt][nt][rg];
                        ss += __shfl_xor(ss, 1); ss += __shfl_xor(ss, 2);
                        ss += __shfl_xor(ss, 4); ss += __shfl_xor(ss, 8);
                        const float inv = 1.0f / (sqrtf(ss) + 1e-8f);
                        const int row = wmoff + mt * 16 + quad * 4 + rg;
#pragma unroll
                        for (int nt = 0; nt < 4; ++nt) {
                            const int colh = (wn & 1) * 64 + nt * 16 + cl;
                            S[row * 128 + (((colh >> 3) ^ (row & 15)) * 8) + (colh & 7)] =
                                (f16)(acc[mt][nt][rg] * inv);
                        }
                    }
            }
            __syncthreads();
#pragma unroll
            for (int i = 0; i < 4; ++i) {
                const int c = tid + i * NT;
                const int s = c >> 4, gi = c & 15;
                f16x8 v = *(const f16x8*)(&S[s * 128 + ((gi ^ (s & 15)) * 8)]);
                const int head = h0 + h * 2 + (gi >> 3), d8 = (gi & 7) * 8;
                *(f16x8*)(C + ((size_t)(b_idx * NH + head) * SEQ + sl0 + s) * HD + d8) = v;
            }
        }
    } else {                              // epi==2: f16 transposed [b,h,d,s], two halves
        f16* C = (f16*)Cout;
        f16* S = (f16*)lds;
#pragma unroll
        for (int h = 0; h < 2; ++h) {
            __syncthreads();
            if ((wn >> 1) == h) {
#pragma unroll
                for (int mt = 0; mt < 4; ++mt) {
                    const int s0 = wmoff + mt * 16 + quad * 4;
#pragma unroll
                    for (int nt = 0; nt < 4; ++nt) {
                        const int colh = (wn & 1) * 64 + nt * 16 + cl;
                        f16x4 o = {(f16)acc[mt][nt][0], (f16)acc[mt][nt][1],
                                   (f16)acc[mt][nt][2], (f16)acc[mt][nt][3]};
                        *(f16x4*)(&S[colh * 128 + (((s0 >> 3) ^ (colh & 15)) * 8) + (s0 & 7)]) = o;
                    }
                }
            }
            __syncthreads();
#pragma unroll
            for (int i = 0; i < 4; ++i) {
                const int c = tid + i * NT;
                const int colh = c >> 4, gi = c & 15;
                f16x8 v = *(const f16x8*)(&S[colh * 128 + ((gi ^ (colh & 15)) * 8)]);
                const int head = h0 + h * 2 + (colh >> 6), d = colh & 63;
                *(f16x8*)(C + ((size_t)(b_idx * NH + head) * HD + d) * SEQ + sl0 + gi * 8) = v;
            }
        }
    }
}

// ---------------------------------------------------------------------------
// Yat attention, round 11: r10 structure, but PV uses mfma_f32_16x16x16_f16.
// Its A-layout (m=lane&15, k=quad*4+i) IS S^T's C-layout (q=cl, k=quad*4+rg),
// so the packed scores feed PV directly — bpermute/cndmask conversion deleted.
// 512 threads (8 waves = 4 wm x 2 wk), 128-q tile, 64-k tiles register-staged
// + dbuf (1 barrier/iter, lgkm drain only). LDS 48 KB.
// ---------------------------------------------------------------------------
__global__ __launch_bounds__(512, 4)
void yat_attn(const f16* __restrict__ Qh, const f16* __restrict__ Kh,
              const f16* __restrict__ Vt, f16* __restrict__ AO)
{
    __shared__ __align__(16) char lds[49152];
    f16* Qs = (f16*)lds;                    // 128 x 64
    f16* KB = (f16*)(lds + 16384);          // 2 bufs x 4096 f16
    f16* VB = (f16*)(lds + 32768);          // 2 bufs x 4096 f16

    const int tid  = threadIdx.x;
    const int lane = tid & 63;
    const int w    = tid >> 6;
    const int cl   = lane & 15;
    const int quad = lane >> 4;
    const int wm = w & 3;                   // q quarter (32 q)
    const int wk = w >> 2;                  // k half (32 k)
    const int q0 = blockIdx.x * 128;
    const int bh = blockIdx.y;

    const f16* Qg = Qh + (size_t)bh * SEQ * HD;
    const f16* Kg = Kh + (size_t)bh * SEQ * HD;
    const f16* Vg = Vt + (size_t)bh * HD * SEQ;

    const int rkv = tid >> 3;               // 0..63
    const int gkv = tid & 7;
    const f16* gK = Kg + (size_t)rkv * HD + gkv * 8;
    const f16* gV = Vg + (size_t)rkv * SEQ + gkv * 8;
    const int lkOff = rkv * 64 + ((gkv ^ (rkv & 7)) * 8);

    f16x8 kr = *(const f16x8*)(gK);
    f16x8 vr = *(const f16x8*)(gV);

#pragma unroll
    for (int i = 0; i < 2; ++i) {
        const int s0 = tid + i * 512;
        const int row = s0 >> 3, g = s0 & 7;
        f16x8 v = *(const f16x8*)(Qg + (size_t)(q0 + row) * HD + g * 8);
        *(f16x8*)(&Qs[row * 64 + ((g ^ (row & 7)) * 8)]) = v;
    }
    __syncthreads();
    f16x8 qf[2][2];
#pragma unroll
    for (int qt = 0; qt < 2; ++qt)
#pragma unroll
        for (int kb = 0; kb < 2; ++kb)
            qf[qt][kb] = *(const f16x8*)(&Qs[(wm * 32 + qt * 16 + cl) * 64 +
                                             ((kb * 4 + quad) ^ (cl & 7)) * 8]);

    f32x4 O[2][4];
    float rs[2] = {0.f, 0.f};
#pragma unroll
    for (int i = 0; i < 2; ++i)
#pragma unroll
        for (int j = 0; j < 4; ++j) O[i][j] = (f32x4){0.f, 0.f, 0.f, 0.f};

    for (int t = 0; t < 32; ++t) {
        const int buf = t & 1;
        *(f16x8*)(&KB[buf * 4096 + lkOff]) = kr;
        *(f16x8*)(&VB[buf * 4096 + lkOff]) = vr;
        if (t < 31) {
            kr = *(const f16x8*)(gK + (size_t)(t + 1) * 64 * HD);
            vr = *(const f16x8*)(gV + (t + 1) * 64);
        }
        __syncthreads();                    // lgkm drain; next loads in flight

        const f16* Ks = KB + buf * 4096;
        const f16* Vs = VB + buf * 4096;

        // ---- S^T (32k x 32q) = K.Q^T, K=32 MFMAs ----
        f32x4 s[2][2];
#pragma unroll
        for (int kt = 0; kt < 2; ++kt)
#pragma unroll
            for (int qt = 0; qt < 2; ++qt) s[kt][qt] = (f32x4){0.f, 0.f, 0.f, 0.f};
#pragma unroll
        for (int kb = 0; kb < 2; ++kb) {
            const int sw = ((kb * 4 + quad) ^ (cl & 7)) * 8;
            f16x8 af0 = *(const f16x8*)(&Ks[(wk * 32 +  0 + cl) * 64 + sw]);
            f16x8 af1 = *(const f16x8*)(&Ks[(wk * 32 + 16 + cl) * 64 + sw]);
#pragma unroll
            for (int qt = 0; qt < 2; ++qt) {
                s[0][qt] = __builtin_amdgcn_mfma_f32_16x16x32_f16(af0, qf[qt][kb], s[0][qt], 0, 0, 0);
                s[1][qt] = __builtin_amdgcn_mfma_f32_16x16x32_f16(af1, qf[qt][kb], s[1][qt], 0, 0, 0);
            }
        }

        // ---- yat scores p = 4.41*rcp(u) + u - 4.2, u = 1.1 - d ----
        // packed pairs ARE the 16x16x16 A-fragments (k = quad*4 + i)
        f16x4 pa16[2][2];
#pragma unroll
        for (int kt = 0; kt < 2; ++kt)
#pragma unroll
            for (int qt = 0; qt < 2; ++qt) {
                float p[4];
#pragma unroll
                for (int rg = 0; rg < 4; ++rg) {
                    const float u = (1.0f + YAT_EPS) - s[kt][qt][rg];
                    p[rg] = fmaf(4.41f, __builtin_amdgcn_rcpf(u), u - 4.2f);
                    rs[qt] += p[rg];
                }
                union { int i2[2]; f16x4 h; } pk_;
                pk_.i2[0] = pk2(p[0], p[1]);
                pk_.i2[1] = pk2(p[2], p[3]);
                pa16[kt][qt] = pk_.h;
            }

        // ---- O += P.V via 16x16x16 MFMAs (k window: wk*32 + kt*16) ----
#pragma unroll
        for (int kt = 0; kt < 2; ++kt)
#pragma unroll
            for (int dn = 0; dn < 4; ++dn) {
                const int row = dn * 16 + cl;
                const int g = wk * 4 + kt * 2 + (quad >> 1);
                f16x4 vb = *(const f16x4*)(&Vs[row * 64 + ((g ^ (row & 7)) * 8) + (quad & 1) * 4]);
#pragma unroll
                for (int qt = 0; qt < 2; ++qt)
                    O[qt][dn] = __builtin_amdgcn_mfma_f32_16x16x16f16(pa16[kt][qt], vb, O[qt][dn], 0, 0, 0);
            }
    }

    // ---- epilogue: cross-wk reduce rs and O, normalize, store ----
    __syncthreads();
    float* rs_s = (float*)lds;
    float* Ox   = (float*)(lds + 1024);

#pragma unroll
    for (int qt = 0; qt < 2; ++qt) {
        float t = rs[qt];
        t += __shfl_xor(t, 16);
        t += __shfl_xor(t, 32);
        if (quad == 0) rs_s[wk * 128 + wm * 32 + qt * 16 + cl] = t;
    }
    if (wk == 1) {
#pragma unroll
        for (int qt = 0; qt < 2; ++qt)
#pragma unroll
            for (int dn = 0; dn < 4; ++dn)
#pragma unroll
                for (int rg = 0; rg < 4; ++rg)
                    Ox[(wm * 32 + qt * 16 + quad * 4 + rg) * 64 + dn * 16 + cl] = O[qt][dn][rg];
    }
    __syncthreads();
    if (wk == 0) {
        const int b = bh >> 4, h = bh & 15;
#pragma unroll
        for (int qt = 0; qt < 2; ++qt)
#pragma unroll
            for (int rg = 0; rg < 4; ++rg) {
                const int ql = wm * 32 + qt * 16 + quad * 4 + rg;
                const float tot = rs_s[ql] + rs_s[128 + ql];
                const float inv = 1.0f / (tot + 1e-6f);
                const size_t rowoff = ((size_t)b * SEQ + q0 + ql) * EDIM + h * 64;
#pragma unroll
                for (int dn = 0; dn < 4; ++dn)
                    AO[rowoff + dn * 16 + cl] =
                        (f16)((O[qt][dn][rg] + Ox[ql * 64 + dn * 16 + cl]) * inv);
            }
    }
}

// ---------------------------------------------------------------------------
extern "C" void kernel_launch(void* const* d_in, const int* in_sizes, int n_in,
                              void* d_out, int out_size, void* d_ws, size_t ws_size,
                              hipStream_t stream)
{
    const float* x  = (const float*)d_in[0];
    const float* Wq = (const float*)d_in[1];
    const float* bq = (const float*)d_in[2];
    const float* Wk = (const float*)d_in[3];
    const float* bk = (const float*)d_in[4];
    const float* Wv = (const float*)d_in[5];
    const float* bv = (const float*)d_in[6];
    const float* Wo = (const float*)d_in[7];
    const float* bo = (const float*)d_in[8];

    char* p = (char*)d_ws;
    f16* xb  = (f16*)p;                 p += (size_t)NROW * EDIM * 2;   // 8 MB
    f16* Wqt = (f16*)p;                 p += (size_t)EDIM * EDIM * 2;   // 2 MB
    f16* Wkt = (f16*)p;                 p += (size_t)EDIM * EDIM * 2;
    f16* Wvt = (f16*)p;                 p += (size_t)EDIM * EDIM * 2;
    f16* Wot = (f16*)p;                 p += (size_t)EDIM * EDIM * 2;
    f16* Qhb = (f16*)p;                 p += (size_t)NROW * EDIM * 2;   // [b,h,s,d]
    f16* Khb = (f16*)p;                 p += (size_t)NROW * EDIM * 2;
    f16* Vtb = (f16*)p;                 p += (size_t)NROW * EDIM * 2;   // [b,h,d,s]
    f16* AOb = (f16*)p;                 p += (size_t)NROW * EDIM * 2;   // [b,s,e]

    // prep: weight transposes (z 0..3) + x cast (z 4) in one launch
    prep_kernel<<<dim3(32, 32, 5), 256, 0, stream>>>(x, xb, Wq, Wk, Wv, Wo,
                                                     Wqt, Wkt, Wvt, Wot);

    // fused Q/K/V projections: 128x256 tiles -> 384 blocks, 512 threads
    gemm_f16<256><<<dim3(NROW / 128, EDIM / 256, 3), 512, 0, stream>>>(
        xb, Wqt, Wkt, Wvt, bq, bk, bv, Qhb, Khb, Vtb, 1, 1, 2);

    yat_attn<<<dim3(SEQ / 128, BATCH * NH), 512, 0, stream>>>(Qhb, Khb, Vtb, AOb);

    // output projection: 128x128 tiles -> 256 blocks, 256 threads
    gemm_f16<128><<<dim3(NROW / 128, EDIM / 128, 1), 256, 0, stream>>>(
        AOb, Wot, Wot, Wot, bo, bo, bo, d_out, d_out, d_out, 0, 0, 0);
}